// Round 4
// baseline (404.452 us; speedup 1.0000x reference)
//
#include <hip/hip_runtime.h>

#define NB   2000   // N
#define HH   4      // heads
#define KK   20     // topk
#define KP   2048   // padded K (j) dim for GEMM
#define GR   16     // rows per k_scores_topk block
#define EPSF 1e-8f

typedef unsigned short ushort;
typedef unsigned long long ull;
using short8   = __attribute__((ext_vector_type(8))) short;
using floatx4  = __attribute__((ext_vector_type(4))) float;
using ushortx4 = __attribute__((ext_vector_type(4))) unsigned short;
using ushortx8 = __attribute__((ext_vector_type(8))) unsigned short;

__device__ inline ushort f2bf(float f) {
    unsigned u = __builtin_bit_cast(unsigned, f);
    u += 0x7fffu + ((u >> 16) & 1u);   // round-to-nearest-even
    return (ushort)(u >> 16);
}

__device__ __forceinline__ void gload_lds16(const ushort* g, ushort* l) {
    __builtin_amdgcn_global_load_lds(
        (const __attribute__((address_space(1))) void*)g,
        (__attribute__((address_space(3))) void*)l, 16, 0, 0);
}

// VALU-only DPP max step: x = max(x, dpp_move(x, CTRL)). Invalid source
// lanes keep old (=x), which is identity for max.
template<int CTRL>
__device__ __forceinline__ float dppmax(float x) {
    int xi = __builtin_bit_cast(int, x);
    int yi = __builtin_amdgcn_update_dpp(xi, xi, CTRL, 0xF, 0xF, false);
    return fmaxf(x, __builtin_bit_cast(float, yi));
}

// After this chain lane 63 holds the wave-wide max (gfx9 wave64 pattern).
__device__ __forceinline__ float wavemax63(float x) {
    x = dppmax<0x111>(x);   // row_shr:1
    x = dppmax<0x112>(x);   // row_shr:2
    x = dppmax<0x114>(x);   // row_shr:4
    x = dppmax<0x118>(x);   // row_shr:8
    x = dppmax<0x142>(x);   // row_bcast:15
    x = dppmax<0x143>(x);   // row_bcast:31
    return x;
}

#define COMP(v,i) ((i)==0?(v).x:(i)==1?(v).y:(i)==2?(v).z:(v).w)

// ---------------------------------------------------------------------------
// Kernel 1 (fused): scores + top-20 for GR=16 rows of one head per block.
// WHY GR=16 (this round): rocprof showed every prior version pinned at
// ~8 TB/s effective L2 bandwidth re-reading e2 (each block streamed the full
// 512KB e2 head-panel; 2000 blocks => 1.02 GB of same-line L2 traffic, all
// 256 CUs contending on the same 2MB). 4x more rows per block => 256 MB.
//   Phase 1 (16 waves, 1024 thr): wave w owns cols w*128 + lane*2 (float2
//     coalesced e2 loads shared across 16 rows); acc[16][2]; raw scores ->
//     LDS scoresS[16][2048] (128KB; 1 block/CU, traffic-bound so OK).
//   Phase 2 (16 waves = 4 row-groups x 4 col-slices): selection body
//     IDENTICAL to the verified previous version (4 rows/wave, 8 cand/lane,
//     DPP wave-max, ballot lowest-lane = lowest idx, packed u64
//     valbits<<32|~idx lists), just indexed by (hw,sl).
//   Phase 3: 4-list merge per row (t<16), exact jax.lax.top_k tiebreak.
// ---------------------------------------------------------------------------
__global__ __launch_bounds__(1024, 2) void k_scores_topk(
    const float* __restrict__ e1, const float* __restrict__ e2,
    const float* __restrict__ temperature,
    int* __restrict__ topk_idx, float* __restrict__ topk_val)
{
    const int h  = blockIdx.y;
    const int n0 = blockIdx.x * GR;
    const int t  = threadIdx.x;
    const int w  = t >> 6, lane = t & 63;

    __shared__ float e1s[GR][64];
    __shared__ float scoresS[GR][2048];
    __shared__ float red[GR][4];
    __shared__ ull   lists[4][GR][KK + 1];
    __shared__ float selpv[GR][KK];
    __shared__ int   seli[GR][KK];
    __shared__ float ssum[GR];

    e1s[t >> 6][t & 63] = e1[(size_t)(h * NB + n0 + (t >> 6)) * 64 + (t & 63)];
    __syncthreads();

    const float rtemp = 1.f / temperature[h];
    const float* __restrict__ e2h = e2 + (size_t)h * 64 * NB;

    // ---- phase 1: GEMM, 16 waves, 2 cols per lane, 16 rows ----
    {
        const int mb1 = w * 128 + lane * 2;           // this lane's 2 cols
        const int ml1 = (mb1 < NB) ? mb1 : (NB - 2);  // clamp tail (dup cols)

        float acc[GR][2];
#pragma unroll
        for (int r = 0; r < GR; r++) { acc[r][0] = 0.f; acc[r][1] = 0.f; }

#pragma unroll 2
        for (int d4 = 0; d4 < 64; d4 += 4) {
            float4 ev[GR];
#pragma unroll
            for (int r = 0; r < GR; r++) ev[r] = *(const float4*)&e1s[r][d4];
#pragma unroll
            for (int dd = 0; dd < 4; dd++) {
                float2 a = *(const float2*)(e2h + (size_t)(d4 + dd) * NB + ml1);
#pragma unroll
                for (int r = 0; r < GR; r++) {
                    float f = COMP(ev[r], dd);
                    acc[r][0] += f * a.x;
                    acc[r][1] += f * a.y;
                }
            }
        }

#pragma unroll
        for (int r = 0; r < GR; r++) {
            float2 v; v.x = acc[r][0]; v.y = acc[r][1];
            *(float2*)&scoresS[r][mb1] = v;   // slot by UNCLAMPED col; tail slots sentineled below
        }
    }
    __syncthreads();

    // ---- phase 2: selection; wave (hw,sl) = 4 rows x one 512-col slice ----
    {
        const int hw = w >> 2;            // row group 0..3 -> rows hw*4..+4
        const int sl = w & 3;             // col slice
        const int  mbase = sl * 512 + lane * 8;
        const bool valid = (mbase < NB);  // all-8-or-none (NB%8==0)

        float acc[4][8];
#pragma unroll
        for (int r = 0; r < 4; r++) {
            float4 lo = *(const float4*)&scoresS[hw * 4 + r][mbase];
            float4 hi = *(const float4*)&scoresS[hw * 4 + r][mbase + 4];
            acc[r][0] = lo.x; acc[r][1] = lo.y; acc[r][2] = lo.z; acc[r][3] = lo.w;
            acc[r][4] = hi.x; acc[r][5] = hi.y; acc[r][6] = hi.z; acc[r][7] = hi.w;
        }

        // tv = relu(acc)*rtemp ; invalid tail lanes -> -1 sentinel
#pragma unroll
        for (int r = 0; r < 4; r++) {
            float tvm = -1.f;
#pragma unroll
            for (int k = 0; k < 8; k++) {
                float v = valid ? fmaxf(acc[r][k], 0.f) * rtemp : -1.f;
                acc[r][k] = v;
                tvm = fmaxf(tvm, v);
            }
            tvm = wavemax63(tvm);
            if (lane == 63) red[hw * 4 + r][sl] = tvm;   // slice max (exp shift)
        }

        // running per-lane local argmax (strict > keeps lowest k)
        float lm[4]; int ak[4];
#pragma unroll
        for (int r = 0; r < 4; r++) {
            float l = acc[r][0]; int a = 0;
#pragma unroll
            for (int k = 1; k < 8; k++)
                if (acc[r][k] > l) { l = acc[r][k]; a = k; }
            lm[r] = l; ak[r] = a;
        }

        // 20 rounds; per round the 4 rows' DPP chains interleave
        for (int round = 0; round < KK; round++) {
            float M[4];
#pragma unroll
            for (int r = 0; r < 4; r++) M[r] = lm[r];
#pragma unroll
            for (int r = 0; r < 4; r++) M[r] = dppmax<0x111>(M[r]);
#pragma unroll
            for (int r = 0; r < 4; r++) M[r] = dppmax<0x112>(M[r]);
#pragma unroll
            for (int r = 0; r < 4; r++) M[r] = dppmax<0x114>(M[r]);
#pragma unroll
            for (int r = 0; r < 4; r++) M[r] = dppmax<0x118>(M[r]);
#pragma unroll
            for (int r = 0; r < 4; r++) M[r] = dppmax<0x142>(M[r]);
#pragma unroll
            for (int r = 0; r < 4; r++) M[r] = dppmax<0x143>(M[r]);
#pragma unroll
            for (int r = 0; r < 4; r++)
                M[r] = __builtin_bit_cast(float,
                         __builtin_amdgcn_readlane(__builtin_bit_cast(int, M[r]), 63));
#pragma unroll
            for (int r = 0; r < 4; r++) {
                ull ball = __ballot(lm[r] == M[r]);
                int wl   = __ffsll(ball) - 1;       // lowest lane = lowest global idx
                if (lane == wl) {
                    int gidx = mbase + ak[r];
                    lists[sl][hw * 4 + r][round] =
                        ((ull)__float_as_uint(M[r]) << 32) | (unsigned)~gidx;
#pragma unroll
                    for (int k = 0; k < 8; k++) if (k == ak[r]) acc[r][k] = -2.f;
                    float l = acc[r][0]; int a = 0;
#pragma unroll
                    for (int k = 1; k < 8; k++)
                        if (acc[r][k] > l) { l = acc[r][k]; a = k; }
                    lm[r] = l; ak[r] = a;
                }
            }
        }
#pragma unroll
        for (int r = 0; r < 4; r++)
            if (lane == 0) lists[sl][hw * 4 + r][KK] = 0ULL;  // merge sentinel
    }
    __syncthreads();

    // merge 4 sorted lists per row; lanes 0..15 of wave 0 handle one row each
    if (t < GR) {
        const int r = t;
        float mx = fmaxf(fmaxf(red[r][0], red[r][1]), fmaxf(red[r][2], red[r][3]));
        int p0 = 0, p1 = 0, p2 = 0, p3 = 0;
        ull h0 = lists[0][r][0], h1 = lists[1][r][0];
        ull h2 = lists[2][r][0], h3 = lists[3][r][0];
        float ss = 0.f;
        for (int q = 0; q < KK; q++) {
            ull a_ = h0 >= h1 ? h0 : h1; int wa = h0 >= h1 ? 0 : 1;
            ull b_ = h2 >= h3 ? h2 : h3; int wb = h2 >= h3 ? 2 : 3;
            ull bk = a_ >= b_ ? a_ : b_; int bw = a_ >= b_ ? wa : wb;
            float tvv = __uint_as_float((unsigned)(bk >> 32));
            float pv  = __expf(tvv - mx);
            selpv[r][q] = pv;
            seli[r][q]  = (int)~(unsigned)bk;
            ss += pv;
            if      (bw == 0) h0 = lists[0][r][++p0];
            else if (bw == 1) h1 = lists[1][r][++p1];
            else if (bw == 2) h2 = lists[2][r][++p2];
            else              h3 = lists[3][r][++p3];
        }
        ssum[r] = ss;
    }
    __syncthreads();

    if (t < GR * KK) {
        int r = t / KK, q = t % KK;
        int o = (h * NB + n0 + r) * KK + q;
        topk_idx[o] = seli[r][q];
        topk_val[o] = selpv[r][q] / (ssum[r] + EPSF);
    }
}

// ---------------------------------------------------------------------------
// Kernel 2: final_adj row i; writes dense fp32 fadj (output) and scatters
// nonzeros into bf16 A-matrix faT_b[m=i][k=j] (pre-zeroed, K padded to 2048).
// ---------------------------------------------------------------------------
__global__ __launch_bounds__(256) void k_final_adj(
    const int* __restrict__ topk_idx, const float* __restrict__ topk_val,
    const float* __restrict__ ew1, const float* __restrict__ eb1,
    const float* __restrict__ ew2, const float* __restrict__ eb2,
    float* __restrict__ fadj_out, ushort* __restrict__ faT_b)
{
    const int i = blockIdx.x;
    const int t = threadIdx.x;

    __shared__ float rows[HH][NB];
    __shared__ float w1[32];
    __shared__ float b1[8];
    __shared__ float w2[8];
    __shared__ float b2v;

    for (int k = t; k < HH * NB; k += 256) ((float*)rows)[k] = 0.f;
    if (t < 32) w1[t] = ew1[t];
    if (t < 8)  { b1[t] = eb1[t]; w2[t] = ew2[t]; }
    if (t == 0) b2v = eb2[0];
    __syncthreads();

    if (t < HH * KK) {
        int h = t / KK, r = t % KK;
        int o = (h * NB + i) * KK + r;
        rows[h][topk_idx[o]] = topk_val[o];
    }
    __syncthreads();

#pragma unroll
    for (int k = 0; k < 8; k++) {
        int j = k * 256 + t;
        if (j < NB) {
            float f0 = rows[0][j], f1 = rows[1][j], f2 = rows[2][j], f3 = rows[3][j];
            float mean = (f0 + f1 + f2 + f3) * 0.25f;
            float outv = 0.f;
            if (mean > 0.f) {
                float ewv = b2v;
#pragma unroll
                for (int c = 0; c < 8; c++) {
                    float hid = f0 * w1[c] + f1 * w1[8 + c] + f2 * w1[16 + c] + f3 * w1[24 + c] + b1[c];
                    hid = fmaxf(hid, 0.f);
                    ewv += hid * w2[c];
                }
                float sig = 1.f / (1.f + expf(-ewv));
                outv = sig * mean;
                faT_b[(size_t)j * KP + i] = f2bf(outv);  // A[m=i][k=j] scatter
            }
            fadj_out[(size_t)i * NB + j] = outv;
        }
    }
}

// ---------------------------------------------------------------------------
// Kernel 3: support S_b[j][bl*64+d] (bf16, j-major) = x[b,j,l,:] @ W
// ---------------------------------------------------------------------------
__global__ __launch_bounds__(256) void k_support(
    const float* __restrict__ x, const float* __restrict__ w,
    ushort* __restrict__ S_b)
{
    const int j = blockIdx.x;
    const int t = threadIdx.x;

    __shared__ float xs[128 * 65];
    __shared__ float ws[64 * 64];

    for (int k = t; k < 4096; k += 256) ws[k] = w[k];
    for (int idx = t; idx < 8192; idx += 256) {
        int b_ = idx >> 11, rem = idx & 2047;
        int bl = (b_ << 5) + (rem >> 6), dd = rem & 63;
        xs[bl * 65 + dd] = x[(size_t)b_ * 4096000 + (size_t)j * 2048 + rem];
    }
    __syncthreads();

    const int dq = t & 15;
    const int g  = t >> 4;
    float acc[8][4];
#pragma unroll
    for (int r = 0; r < 8; r++)
#pragma unroll
        for (int c = 0; c < 4; c++) acc[r][c] = 0.f;

    for (int dd = 0; dd < 64; dd++) {
        float4 w4 = *(const float4*)&ws[dd * 64 + dq * 4];
#pragma unroll
        for (int r = 0; r < 8; r++) {
            float xv = xs[(g * 8 + r) * 65 + dd];
            acc[r][0] += xv * w4.x;
            acc[r][1] += xv * w4.y;
            acc[r][2] += xv * w4.z;
            acc[r][3] += xv * w4.w;
        }
    }

#pragma unroll
    for (int r = 0; r < 8; r++) {
        int bl = g * 8 + r;
        ushortx4 v;
        v.x = f2bf(acc[r][0]); v.y = f2bf(acc[r][1]);
        v.z = f2bf(acc[r][2]); v.w = f2bf(acc[r][3]);
        *(ushortx4*)&S_b[(size_t)j * 8192 + bl * 64 + dq * 4] = v;
    }
}

// ---------------------------------------------------------------------------
// Kernel 4: transpose S_b[j][c] (2000x8192 bf16) -> ST[c][j] (8192xKP bf16),
// zero-padding j in [2000,2048). 64x64 tiles via LDS.
// ---------------------------------------------------------------------------
__global__ __launch_bounds__(256) void k_transpose(
    const ushort* __restrict__ S_b, ushort* __restrict__ ST)
{
    const int jt = blockIdx.x;   // 0..31
    const int ct = blockIdx.y;   // 0..127
    const int t  = threadIdx.x;

    __shared__ ushort tile[64 * 65];

#pragma unroll
    for (int p = 0; p < 4; p++) {
        int q = p * 256 + t;
        int row = q >> 4, seg = q & 15;
        int j = jt * 64 + row;
        ushort v0 = 0, v1 = 0, v2 = 0, v3 = 0;
        if (j < NB) {
            const ushort* src = &S_b[(size_t)j * 8192 + ct * 64 + seg * 4];
            v0 = src[0]; v1 = src[1]; v2 = src[2]; v3 = src[3];
        }
        ushort* dst = &tile[row * 65 + seg * 4];
        dst[0] = v0; dst[1] = v1; dst[2] = v2; dst[3] = v3;
    }
    __syncthreads();

#pragma unroll
    for (int p = 0; p < 2; p++) {
        int q = p * 256 + t;
        int rc = q >> 3, s = q & 7;
        ushortx8 o;
#pragma unroll
        for (int k = 0; k < 8; k++) o[k] = tile[(s * 8 + k) * 65 + rc];
        *(ushortx8*)&ST[(size_t)(ct * 64 + rc) * KP + jt * 64 + s * 8] = o;
    }
}

// ---------------------------------------------------------------------------
// Kernel 5: MFMA bf16 GEMM: out[i][c] = sum_j A[i][j] * B[c][j]
// global_load_lds width=16 staging; XOR swizzle applied on the GLOBAL fetch
// side (LDS image lane-linear), frag ds_read_b128 conflict-free.
// ---------------------------------------------------------------------------
__global__ __launch_bounds__(256) void k_gemm(
    const ushort* __restrict__ A, const ushort* __restrict__ B,
    const float* __restrict__ bias, float* __restrict__ out)
{
    __shared__ ushort As[128 * 64];
    __shared__ ushort Bs[128 * 64];

    const int t    = threadIdx.x;
    const int lane = t & 63, wave = t >> 6;
    const int wm   = wave & 1, wn = wave >> 1;
    const int i0   = blockIdx.x * 128;
    const int c0   = blockIdx.y * 128;

    const int lr = lane >> 3;   // local row within 8-row chunk
    const int dg = lane & 7;    // LDS dest group (fixed by lane-linear DMA)

    floatx4 acc[4][4];
#pragma unroll
    for (int r = 0; r < 4; r++)
#pragma unroll
        for (int c = 0; c < 4; c++) acc[r][c] = (floatx4)(0.f);

    for (int kb = 0; kb < 32; kb++) {
        __syncthreads();
#pragma unroll
        for (int p = 0; p < 4; p++) {
            int rowb = p * 32 + wave * 8;           // chunk base row (mult of 8)
            int row  = rowb + lr;
            int g    = dg ^ lr;                     // row&7 == lr here
            const ushort* ga = &A[(size_t)(i0 + row) * KP + kb * 64 + g * 8];
            const ushort* gb = &B[(size_t)(c0 + row) * KP + kb * 64 + g * 8];
            gload_lds16(ga, &As[rowb * 64]);
            gload_lds16(gb, &Bs[rowb * 64]);
        }
        __syncthreads();   // compiler emits s_waitcnt vmcnt(0) before barrier

#pragma unroll
        for (int kk = 0; kk < 2; kk++) {
            short8 af[4], bf[4];
            const int gidx = kk * 4 + (lane >> 4);   // global k-group 0..7
            const int dsw  = gidx ^ (lane & 7);      // m&7 == lane&7 for frag rows
#pragma unroll
            for (int r = 0; r < 4; r++) {
                int m = wm * 64 + r * 16 + (lane & 15);
                af[r] = *(const short8*)&As[m * 64 + dsw * 8];
            }
#pragma unroll
            for (int c = 0; c < 4; c++) {
                int m = wn * 64 + c * 16 + (lane & 15);
                bf[c] = *(const short8*)&Bs[m * 64 + dsw * 8];
            }
#pragma unroll
            for (int r = 0; r < 4; r++)
#pragma unroll
                for (int c = 0; c < 4; c++)
                    acc[r][c] = __builtin_amdgcn_mfma_f32_16x16x32_bf16(af[r], bf[c], acc[r][c], 0, 0, 0);
        }
    }

    // epilogue: D layout col = lane&15, row = (lane>>4)*4 + reg  [m89-verified]
    const int mq = (lane >> 4) * 4;
    const int nn = lane & 15;
#pragma unroll
    for (int r = 0; r < 4; r++) {
#pragma unroll
        for (int c = 0; c < 4; c++) {
            int cg = c0 + wn * 64 + c * 16 + nn;
            float bv = bias[cg & 63];
            int b_ = cg >> 11, rem = cg & 2047;
            float* op = out + (size_t)b_ * 4096000 + rem;
#pragma unroll
            for (int rg = 0; rg < 4; rg++) {
                int i = i0 + wm * 64 + r * 16 + mq + rg;
                if (i < NB) op[(size_t)i * 2048] = acc[r][c][rg] + bv;
            }
        }
    }
}

// ---------------------------------------------------------------------------
extern "C" void kernel_launch(void* const* d_in, const int* in_sizes, int n_in,
                              void* d_out, int out_size, void* d_ws, size_t ws_size,
                              hipStream_t stream)
{
    const float* x           = (const float*)d_in[0];
    const float* e1          = (const float*)d_in[1];
    const float* e2          = (const float*)d_in[2];
    const float* temperature = (const float*)d_in[3];
    const float* ew1         = (const float*)d_in[4];
    const float* eb1         = (const float*)d_in[5];
    const float* ew2         = (const float*)d_in[6];
    const float* eb2         = (const float*)d_in[7];
    const float* weight      = (const float*)d_in[8];
    const float* bias        = (const float*)d_in[9];

    float* out  = (float*)d_out;            // (B,N,L,DOUT) = 16,384,000 floats
    float* fadj = out + 16384000;           // (N,N)        =  4,000,000 floats

    // workspace:
    //   ST    bf16 8192xKP   = 33,554,432 B
    //   S_b   bf16 2000x8192 = 32,768,000 B
    //   faT_b bf16 KPxKP     =  8,388,608 B
    //   topk  idx+val        =  1,280,000 B      total ~76.0 MB
    ushort* ST       = (ushort*)d_ws;
    ushort* S_b      = ST + (size_t)8192 * KP;
    ushort* faT_b    = (ushort*)((char*)d_ws + 66322432u);
    int*    topk_idx = (int*)(faT_b + (size_t)KP * KP);
    float*  topk_val = (float*)(topk_idx + 160000);

    hipMemsetAsync(faT_b, 0, (size_t)KP * KP * sizeof(ushort), stream);

    k_scores_topk<<<dim3(NB / GR, HH), 1024, 0, stream>>>(e1, e2, temperature,
                                                          topk_idx, topk_val);
    k_final_adj<<<NB, 256, 0, stream>>>(topk_idx, topk_val, ew1, eb1, ew2, eb2,
                                        fadj, faT_b);
    k_support<<<NB, 256, 0, stream>>>(x, weight, S_b);
    k_transpose<<<dim3(32, 128), 256, 0, stream>>>(S_b, ST);
    k_gemm<<<dim3(16, 64), 256, 0, stream>>>(faT_b, ST, bias, out);
}

// Round 5
// 392.858 us; speedup vs baseline: 1.0295x; 1.0295x over previous
//
#include <hip/hip_runtime.h>

#define NB   2000   // N
#define HH   4      // heads
#define KK   20     // topk
#define KP   2048   // padded K (j) dim for GEMM
#define GA   4      // rows per k_scores_topk block
#define EPSF 1e-8f

typedef unsigned short ushort;
typedef unsigned long long ull;
using short8   = __attribute__((ext_vector_type(8))) short;
using floatx4  = __attribute__((ext_vector_type(4))) float;
using ushortx4 = __attribute__((ext_vector_type(4))) unsigned short;
using ushortx8 = __attribute__((ext_vector_type(8))) unsigned short;

__device__ inline ushort f2bf(float f) {
    unsigned u = __builtin_bit_cast(unsigned, f);
    u += 0x7fffu + ((u >> 16) & 1u);   // round-to-nearest-even
    return (ushort)(u >> 16);
}

__device__ __forceinline__ void gload_lds16(const ushort* g, ushort* l) {
    __builtin_amdgcn_global_load_lds(
        (const __attribute__((address_space(1))) void*)g,
        (__attribute__((address_space(3))) void*)l, 16, 0, 0);
}

// VALU-only DPP max step: x = max(x, dpp_move(x, CTRL)). Invalid source
// lanes keep old (=x), which is identity for max.
template<int CTRL>
__device__ __forceinline__ float dppmax(float x) {
    int xi = __builtin_bit_cast(int, x);
    int yi = __builtin_amdgcn_update_dpp(xi, xi, CTRL, 0xF, 0xF, false);
    return fmaxf(x, __builtin_bit_cast(float, yi));
}

// After this chain lane 63 holds the wave-wide max (gfx9 wave64 pattern:
// row_shr 1/2/4/8 within rows of 16, then row_bcast15 / row_bcast31).
__device__ __forceinline__ float wavemax63(float x) {
    x = dppmax<0x111>(x);   // row_shr:1
    x = dppmax<0x112>(x);   // row_shr:2
    x = dppmax<0x114>(x);   // row_shr:4
    x = dppmax<0x118>(x);   // row_shr:8
    x = dppmax<0x142>(x);   // row_bcast:15
    x = dppmax<0x143>(x);   // row_bcast:31
    return x;
}

#define COMP(v,i) ((i)==0?(v).x:(i)==1?(v).y:(i)==2?(v).z:(v).w)

// ---------------------------------------------------------------------------
// Kernel 1 (fused): scores + top-20 in score domain for GA=4 rows of one head.
// __launch_bounds__(512, 4) (THIS ROUND'S CHANGE): every prior version
// reported VGPR_Count 32-64 while phase 2 needs ~60 live VGPRs (acc[4][8]=32
// + lm/ak/M + addressing) => the compiler, targeting 8 waves/EU, spilled the
// selection candidate array to scratch. Each of the 80 winner-update rounds
// then re-loaded 8 candidates via buffer_load (~200cy each + spill VALU),
// explaining the 4x gap between static VALU count and measured VALU-issue
// time, invariant across r2/r3/r4 structures (~127us floor, VALUBusy ~77%).
// min-waves/EU=4 => 128-VGPR budget => no spill; occupancy 2 blocks/CU is
// enough since the kernel was spill-issue-bound, not latency-hiding-bound.
//   Phase 1 (8 waves): GEMM, wave owns 4 cols/lane (16 acc), scores -> LDS.
//   Phase 2 (waves 0-3): selection (DPP wave-max, ballot lowest-lane =
//     lowest idx, packed u64 valbits<<32|~idx lists).
//   Phase 3: 4-list merge per row, exact jax.lax.top_k tiebreak.
// ---------------------------------------------------------------------------
__global__ __launch_bounds__(512, 4) void k_scores_topk(
    const float* __restrict__ e1, const float* __restrict__ e2,
    const float* __restrict__ temperature,
    int* __restrict__ topk_idx, float* __restrict__ topk_val)
{
    const int h  = blockIdx.y;
    const int n0 = blockIdx.x * GA;
    const int t  = threadIdx.x;
    const int w  = t >> 6, lane = t & 63;

    __shared__ float e1s[GA][64];
    __shared__ float scoresS[GA][2048];
    __shared__ float red[GA][4];
    __shared__ ull   lists[4][GA][KK + 1];
    __shared__ float selpv[GA][KK];
    __shared__ int   seli[GA][KK];
    __shared__ float ssum[GA];

    if (t < 256)
        e1s[t >> 6][t & 63] = e1[(size_t)(h * NB + n0 + (t >> 6)) * 64 + (t & 63)];
    __syncthreads();

    const float rtemp = 1.f / temperature[h];
    const float* __restrict__ e2h = e2 + (size_t)h * 64 * NB;

    // ---- phase 1: GEMM, 8 waves, 4 cols per lane (16 accumulators) ----
    {
        const int mb1 = w * 256 + lane * 4;           // this lane's 4 cols
        const int ml1 = (mb1 < NB) ? mb1 : (NB - 4);  // clamp tail (dup cols)

        float acc[GA][4];
#pragma unroll
        for (int r = 0; r < GA; r++)
#pragma unroll
            for (int c = 0; c < 4; c++) acc[r][c] = 0.f;

        for (int d4 = 0; d4 < 64; d4 += 4) {
            float4 ev0 = *(const float4*)&e1s[0][d4];
            float4 ev1 = *(const float4*)&e1s[1][d4];
            float4 ev2 = *(const float4*)&e1s[2][d4];
            float4 ev3 = *(const float4*)&e1s[3][d4];
#pragma unroll
            for (int dd = 0; dd < 4; dd++) {
                float4 a = *(const float4*)(e2h + (size_t)(d4 + dd) * NB + ml1);
                float f0 = COMP(ev0, dd), f1 = COMP(ev1, dd);
                float f2 = COMP(ev2, dd), f3 = COMP(ev3, dd);
                acc[0][0] += f0*a.x; acc[0][1] += f0*a.y; acc[0][2] += f0*a.z; acc[0][3] += f0*a.w;
                acc[1][0] += f1*a.x; acc[1][1] += f1*a.y; acc[1][2] += f1*a.z; acc[1][3] += f1*a.w;
                acc[2][0] += f2*a.x; acc[2][1] += f2*a.y; acc[2][2] += f2*a.z; acc[2][3] += f2*a.w;
                acc[3][0] += f3*a.x; acc[3][1] += f3*a.y; acc[3][2] += f3*a.z; acc[3][3] += f3*a.w;
            }
        }

#pragma unroll
        for (int r = 0; r < GA; r++) {
            float4 v; v.x = acc[r][0]; v.y = acc[r][1]; v.z = acc[r][2]; v.w = acc[r][3];
            *(float4*)&scoresS[r][mb1] = v;   // LDS slot by UNCLAMPED col; tail slots garbage, sentineled below
        }
    }
    __syncthreads();

    // ---- phases 2+3: selection, waves 0-3 only (identical semantics) ----
    if (w < 4) {
        const int  mbase = w * 512 + lane * 8;
        const bool valid = (mbase < NB);            // all-8-or-none (NB%8==0)

        float acc[GA][8];
#pragma unroll
        for (int r = 0; r < GA; r++) {
            float4 lo = *(const float4*)&scoresS[r][mbase];
            float4 hi = *(const float4*)&scoresS[r][mbase + 4];
            acc[r][0] = lo.x; acc[r][1] = lo.y; acc[r][2] = lo.z; acc[r][3] = lo.w;
            acc[r][4] = hi.x; acc[r][5] = hi.y; acc[r][6] = hi.z; acc[r][7] = hi.w;
        }

        // tv = relu(acc)*rtemp ; invalid tail lanes -> -1 sentinel (< any valid tv)
#pragma unroll
        for (int r = 0; r < GA; r++) {
            float tvm = -1.f;
#pragma unroll
            for (int k = 0; k < 8; k++) {
                float v = valid ? fmaxf(acc[r][k], 0.f) * rtemp : -1.f;
                acc[r][k] = v;
                tvm = fmaxf(tvm, v);
            }
            tvm = wavemax63(tvm);
            if (lane == 63) red[r][w] = tvm;   // slice max (for exp shift)
        }

        // running per-lane local argmax for each row (strict > keeps lowest k)
        float lm[GA]; int ak[GA];
#pragma unroll
        for (int r = 0; r < GA; r++) {
            float l = acc[r][0]; int a = 0;
#pragma unroll
            for (int k = 1; k < 8; k++)
                if (acc[r][k] > l) { l = acc[r][k]; a = k; }
            lm[r] = l; ak[r] = a;
        }

        // selection: 20 rounds; per round all 4 rows' DPP chains interleaved
        for (int round = 0; round < KK; round++) {
            float M[GA];
#pragma unroll
            for (int r = 0; r < GA; r++) M[r] = lm[r];
#pragma unroll
            for (int r = 0; r < GA; r++) M[r] = dppmax<0x111>(M[r]);
#pragma unroll
            for (int r = 0; r < GA; r++) M[r] = dppmax<0x112>(M[r]);
#pragma unroll
            for (int r = 0; r < GA; r++) M[r] = dppmax<0x114>(M[r]);
#pragma unroll
            for (int r = 0; r < GA; r++) M[r] = dppmax<0x118>(M[r]);
#pragma unroll
            for (int r = 0; r < GA; r++) M[r] = dppmax<0x142>(M[r]);
#pragma unroll
            for (int r = 0; r < GA; r++) M[r] = dppmax<0x143>(M[r]);
#pragma unroll
            for (int r = 0; r < GA; r++)
                M[r] = __builtin_bit_cast(float,
                         __builtin_amdgcn_readlane(__builtin_bit_cast(int, M[r]), 63));
#pragma unroll
            for (int r = 0; r < GA; r++) {
                ull ball = __ballot(lm[r] == M[r]);
                int wl   = __ffsll(ball) - 1;       // lowest lane = lowest global idx
                if (lane == wl) {
                    int gidx = mbase + ak[r];
                    lists[w][r][round] =
                        ((ull)__float_as_uint(M[r]) << 32) | (unsigned)~gidx;
#pragma unroll
                    for (int k = 0; k < 8; k++) if (k == ak[r]) acc[r][k] = -2.f;
                    float l = acc[r][0]; int a = 0;
#pragma unroll
                    for (int k = 1; k < 8; k++)
                        if (acc[r][k] > l) { l = acc[r][k]; a = k; }
                    lm[r] = l; ak[r] = a;
                }
            }
        }
#pragma unroll
        for (int r = 0; r < GA; r++)
            if (lane == 0) lists[w][r][KK] = 0ULL;  // merge sentinel
    }
    __syncthreads();

    // merge 4 sorted lists per row; lanes 0..3 of wave 0 handle one row each
    if (t < GA) {
        const int r = t;
        float mx = fmaxf(fmaxf(red[r][0], red[r][1]), fmaxf(red[r][2], red[r][3]));
        int p0 = 0, p1 = 0, p2 = 0, p3 = 0;
        ull h0 = lists[0][r][0], h1 = lists[1][r][0];
        ull h2 = lists[2][r][0], h3 = lists[3][r][0];
        float ss = 0.f;
        for (int q = 0; q < KK; q++) {
            ull a_ = h0 >= h1 ? h0 : h1; int wa = h0 >= h1 ? 0 : 1;
            ull b_ = h2 >= h3 ? h2 : h3; int wb = h2 >= h3 ? 2 : 3;
            ull bk = a_ >= b_ ? a_ : b_; int bw = a_ >= b_ ? wa : wb;
            float tvv = __uint_as_float((unsigned)(bk >> 32));
            float pv  = __expf(tvv - mx);
            selpv[r][q] = pv;
            seli[r][q]  = (int)~(unsigned)bk;
            ss += pv;
            if      (bw == 0) h0 = lists[0][r][++p0];
            else if (bw == 1) h1 = lists[1][r][++p1];
            else if (bw == 2) h2 = lists[2][r][++p2];
            else              h3 = lists[3][r][++p3];
        }
        ssum[r] = ss;
    }
    __syncthreads();

    if (t < GA * KK) {
        int r = t / KK, q = t % KK;
        int o = (h * NB + n0 + r) * KK + q;
        topk_idx[o] = seli[r][q];
        topk_val[o] = selpv[r][q] / (ssum[r] + EPSF);
    }
}

// ---------------------------------------------------------------------------
// Kernel 2: final_adj row i; writes dense fp32 fadj (output) and scatters
// nonzeros into bf16 A-matrix faT_b[m=i][k=j] (pre-zeroed, K padded to 2048).
// ---------------------------------------------------------------------------
__global__ __launch_bounds__(256) void k_final_adj(
    const int* __restrict__ topk_idx, const float* __restrict__ topk_val,
    const float* __restrict__ ew1, const float* __restrict__ eb1,
    const float* __restrict__ ew2, const float* __restrict__ eb2,
    float* __restrict__ fadj_out, ushort* __restrict__ faT_b)
{
    const int i = blockIdx.x;
    const int t = threadIdx.x;

    __shared__ float rows[HH][NB];
    __shared__ float w1[32];
    __shared__ float b1[8];
    __shared__ float w2[8];
    __shared__ float b2v;

    for (int k = t; k < HH * NB; k += 256) ((float*)rows)[k] = 0.f;
    if (t < 32) w1[t] = ew1[t];
    if (t < 8)  { b1[t] = eb1[t]; w2[t] = ew2[t]; }
    if (t == 0) b2v = eb2[0];
    __syncthreads();

    if (t < HH * KK) {
        int h = t / KK, r = t % KK;
        int o = (h * NB + i) * KK + r;
        rows[h][topk_idx[o]] = topk_val[o];
    }
    __syncthreads();

#pragma unroll
    for (int k = 0; k < 8; k++) {
        int j = k * 256 + t;
        if (j < NB) {
            float f0 = rows[0][j], f1 = rows[1][j], f2 = rows[2][j], f3 = rows[3][j];
            float mean = (f0 + f1 + f2 + f3) * 0.25f;
            float outv = 0.f;
            if (mean > 0.f) {
                float ewv = b2v;
#pragma unroll
                for (int c = 0; c < 8; c++) {
                    float hid = f0 * w1[c] + f1 * w1[8 + c] + f2 * w1[16 + c] + f3 * w1[24 + c] + b1[c];
                    hid = fmaxf(hid, 0.f);
                    ewv += hid * w2[c];
                }
                float sig = 1.f / (1.f + expf(-ewv));
                outv = sig * mean;
                faT_b[(size_t)j * KP + i] = f2bf(outv);  // A[m=i][k=j] scatter
            }
            fadj_out[(size_t)i * NB + j] = outv;
        }
    }
}

// ---------------------------------------------------------------------------
// Kernel 3: support S_b[j][bl*64+d] (bf16, j-major) = x[b,j,l,:] @ W
// ---------------------------------------------------------------------------
__global__ __launch_bounds__(256) void k_support(
    const float* __restrict__ x, const float* __restrict__ w,
    ushort* __restrict__ S_b)
{
    const int j = blockIdx.x;
    const int t = threadIdx.x;

    __shared__ float xs[128 * 65];
    __shared__ float ws[64 * 64];

    for (int k = t; k < 4096; k += 256) ws[k] = w[k];
    for (int idx = t; idx < 8192; idx += 256) {
        int b_ = idx >> 11, rem = idx & 2047;
        int bl = (b_ << 5) + (rem >> 6), dd = rem & 63;
        xs[bl * 65 + dd] = x[(size_t)b_ * 4096000 + (size_t)j * 2048 + rem];
    }
    __syncthreads();

    const int dq = t & 15;
    const int g  = t >> 4;
    float acc[8][4];
#pragma unroll
    for (int r = 0; r < 8; r++)
#pragma unroll
        for (int c = 0; c < 4; c++) acc[r][c] = 0.f;

    for (int dd = 0; dd < 64; dd++) {
        float4 w4 = *(const float4*)&ws[dd * 64 + dq * 4];
#pragma unroll
        for (int r = 0; r < 8; r++) {
            float xv = xs[(g * 8 + r) * 65 + dd];
            acc[r][0] += xv * w4.x;
            acc[r][1] += xv * w4.y;
            acc[r][2] += xv * w4.z;
            acc[r][3] += xv * w4.w;
        }
    }

#pragma unroll
    for (int r = 0; r < 8; r++) {
        int bl = g * 8 + r;
        ushortx4 v;
        v.x = f2bf(acc[r][0]); v.y = f2bf(acc[r][1]);
        v.z = f2bf(acc[r][2]); v.w = f2bf(acc[r][3]);
        *(ushortx4*)&S_b[(size_t)j * 8192 + bl * 64 + dq * 4] = v;
    }
}

// ---------------------------------------------------------------------------
// Kernel 4: transpose S_b[j][c] (2000x8192 bf16) -> ST[c][j] (8192xKP bf16),
// zero-padding j in [2000,2048). 64x64 tiles via LDS.
// ---------------------------------------------------------------------------
__global__ __launch_bounds__(256) void k_transpose(
    const ushort* __restrict__ S_b, ushort* __restrict__ ST)
{
    const int jt = blockIdx.x;   // 0..31
    const int ct = blockIdx.y;   // 0..127
    const int t  = threadIdx.x;

    __shared__ ushort tile[64 * 65];

#pragma unroll
    for (int p = 0; p < 4; p++) {
        int q = p * 256 + t;
        int row = q >> 4, seg = q & 15;
        int j = jt * 64 + row;
        ushort v0 = 0, v1 = 0, v2 = 0, v3 = 0;
        if (j < NB) {
            const ushort* src = &S_b[(size_t)j * 8192 + ct * 64 + seg * 4];
            v0 = src[0]; v1 = src[1]; v2 = src[2]; v3 = src[3];
        }
        ushort* dst = &tile[row * 65 + seg * 4];
        dst[0] = v0; dst[1] = v1; dst[2] = v2; dst[3] = v3;
    }
    __syncthreads();

#pragma unroll
    for (int p = 0; p < 2; p++) {
        int q = p * 256 + t;
        int rc = q >> 3, s = q & 7;
        ushortx8 o;
#pragma unroll
        for (int k = 0; k < 8; k++) o[k] = tile[(s * 8 + k) * 65 + rc];
        *(ushortx8*)&ST[(size_t)(ct * 64 + rc) * KP + jt * 64 + s * 8] = o;
    }
}

// ---------------------------------------------------------------------------
// Kernel 5: MFMA bf16 GEMM: out[i][c] = sum_j A[i][j] * B[c][j]
// global_load_lds width=16 staging; XOR swizzle applied on the GLOBAL fetch
// side (LDS image lane-linear), frag ds_read_b128 conflict-free.
// ---------------------------------------------------------------------------
__global__ __launch_bounds__(256) void k_gemm(
    const ushort* __restrict__ A, const ushort* __restrict__ B,
    const float* __restrict__ bias, float* __restrict__ out)
{
    __shared__ ushort As[128 * 64];
    __shared__ ushort Bs[128 * 64];

    const int t    = threadIdx.x;
    const int lane = t & 63, wave = t >> 6;
    const int wm   = wave & 1, wn = wave >> 1;
    const int i0   = blockIdx.x * 128;
    const int c0   = blockIdx.y * 128;

    const int lr = lane >> 3;   // local row within 8-row chunk
    const int dg = lane & 7;    // LDS dest group (fixed by lane-linear DMA)

    floatx4 acc[4][4];
#pragma unroll
    for (int r = 0; r < 4; r++)
#pragma unroll
        for (int c = 0; c < 4; c++) acc[r][c] = (floatx4)(0.f);

    for (int kb = 0; kb < 32; kb++) {
        __syncthreads();
#pragma unroll
        for (int p = 0; p < 4; p++) {
            int rowb = p * 32 + wave * 8;           // chunk base row (mult of 8)
            int row  = rowb + lr;
            int g    = dg ^ lr;                     // row&7 == lr here
            const ushort* ga = &A[(size_t)(i0 + row) * KP + kb * 64 + g * 8];
            const ushort* gb = &B[(size_t)(c0 + row) * KP + kb * 64 + g * 8];
            gload_lds16(ga, &As[rowb * 64]);
            gload_lds16(gb, &Bs[rowb * 64]);
        }
        __syncthreads();   // compiler emits s_waitcnt vmcnt(0) before barrier

#pragma unroll
        for (int kk = 0; kk < 2; kk++) {
            short8 af[4], bf[4];
            const int gidx = kk * 4 + (lane >> 4);   // global k-group 0..7
            const int dsw  = gidx ^ (lane & 7);      // m&7 == lane&7 for frag rows
#pragma unroll
            for (int r = 0; r < 4; r++) {
                int m = wm * 64 + r * 16 + (lane & 15);
                af[r] = *(const short8*)&As[m * 64 + dsw * 8];
            }
#pragma unroll
            for (int c = 0; c < 4; c++) {
                int m = wn * 64 + c * 16 + (lane & 15);
                bf[c] = *(const short8*)&Bs[m * 64 + dsw * 8];
            }
#pragma unroll
            for (int r = 0; r < 4; r++)
#pragma unroll
                for (int c = 0; c < 4; c++)
                    acc[r][c] = __builtin_amdgcn_mfma_f32_16x16x32_bf16(af[r], bf[c], acc[r][c], 0, 0, 0);
        }
    }

    // epilogue: D layout col = lane&15, row = (lane>>4)*4 + reg  [m89-verified]
    const int mq = (lane >> 4) * 4;
    const int nn = lane & 15;
#pragma unroll
    for (int r = 0; r < 4; r++) {
#pragma unroll
        for (int c = 0; c < 4; c++) {
            int cg = c0 + wn * 64 + c * 16 + nn;
            float bv = bias[cg & 63];
            int b_ = cg >> 11, rem = cg & 2047;
            float* op = out + (size_t)b_ * 4096000 + rem;
#pragma unroll
            for (int rg = 0; rg < 4; rg++) {
                int i = i0 + wm * 64 + r * 16 + mq + rg;
                if (i < NB) op[(size_t)i * 2048] = acc[r][c][rg] + bv;
            }
        }
    }
}

// ---------------------------------------------------------------------------
extern "C" void kernel_launch(void* const* d_in, const int* in_sizes, int n_in,
                              void* d_out, int out_size, void* d_ws, size_t ws_size,
                              hipStream_t stream)
{
    const float* x           = (const float*)d_in[0];
    const float* e1          = (const float*)d_in[1];
    const float* e2          = (const float*)d_in[2];
    const float* temperature = (const float*)d_in[3];
    const float* ew1         = (const float*)d_in[4];
    const float* eb1         = (const float*)d_in[5];
    const float* ew2         = (const float*)d_in[6];
    const float* eb2         = (const float*)d_in[7];
    const float* weight      = (const float*)d_in[8];
    const float* bias        = (const float*)d_in[9];

    float* out  = (float*)d_out;            // (B,N,L,DOUT) = 16,384,000 floats
    float* fadj = out + 16384000;           // (N,N)        =  4,000,000 floats

    // workspace:
    //   ST    bf16 8192xKP   = 33,554,432 B
    //   S_b   bf16 2000x8192 = 32,768,000 B
    //   faT_b bf16 KPxKP     =  8,388,608 B
    //   topk  idx+val        =  1,280,000 B      total ~76.0 MB
    ushort* ST       = (ushort*)d_ws;
    ushort* S_b      = ST + (size_t)8192 * KP;
    ushort* faT_b    = (ushort*)((char*)d_ws + 66322432u);
    int*    topk_idx = (int*)(faT_b + (size_t)KP * KP);
    float*  topk_val = (float*)(topk_idx + 160000);

    hipMemsetAsync(faT_b, 0, (size_t)KP * KP * sizeof(ushort), stream);

    k_scores_topk<<<dim3(NB / GA, HH), 512, 0, stream>>>(e1, e2, temperature,
                                                         topk_idx, topk_val);
    k_final_adj<<<NB, 256, 0, stream>>>(topk_idx, topk_val, ew1, eb1, ew2, eb2,
                                        fadj, faT_b);
    k_support<<<NB, 256, 0, stream>>>(x, weight, S_b);
    k_transpose<<<dim3(32, 128), 256, 0, stream>>>(S_b, ST);
    k_gemm<<<dim3(16, 64), 256, 0, stream>>>(faT_b, ST, bias, out);
}

// Round 6
// 372.263 us; speedup vs baseline: 1.0865x; 1.0553x over previous
//
#include <hip/hip_runtime.h>

#define NB   2000   // N
#define HH   4      // heads
#define KK   20     // topk
#define KP   2048   // padded K (j) dim for GEMM
#define GA   4      // rows per k_scores_topk block
#define EPSF 1e-8f

typedef unsigned short ushort;
typedef unsigned long long ull;
using short8   = __attribute__((ext_vector_type(8))) short;
using floatx4  = __attribute__((ext_vector_type(4))) float;
using ushortx4 = __attribute__((ext_vector_type(4))) unsigned short;
using ushortx8 = __attribute__((ext_vector_type(8))) unsigned short;

__device__ inline ushort f2bf(float f) {
    unsigned u = __builtin_bit_cast(unsigned, f);
    u += 0x7fffu + ((u >> 16) & 1u);   // round-to-nearest-even
    return (ushort)(u >> 16);
}

__device__ __forceinline__ void gload_lds16(const ushort* g, ushort* l) {
    __builtin_amdgcn_global_load_lds(
        (const __attribute__((address_space(1))) void*)g,
        (__attribute__((address_space(3))) void*)l, 16, 0, 0);
}

// VALU-only DPP max step: x = max(x, dpp_move(x, CTRL)). Invalid source
// lanes keep old (=x), which is identity for max.
template<int CTRL>
__device__ __forceinline__ float dppmax(float x) {
    int xi = __builtin_bit_cast(int, x);
    int yi = __builtin_amdgcn_update_dpp(xi, xi, CTRL, 0xF, 0xF, false);
    return fmaxf(x, __builtin_bit_cast(float, yi));
}

// After this chain lane 63 holds the wave-wide max (gfx9 wave64 pattern).
__device__ __forceinline__ float wavemax63(float x) {
    x = dppmax<0x111>(x);   // row_shr:1
    x = dppmax<0x112>(x);   // row_shr:2
    x = dppmax<0x114>(x);   // row_shr:4
    x = dppmax<0x118>(x);   // row_shr:8
    x = dppmax<0x142>(x);   // row_bcast:15
    x = dppmax<0x143>(x);   // row_bcast:31
    return x;
}

#define COMP(v,i) ((i)==0?(v).x:(i)==1?(v).y:(i)==2?(v).z:(v).w)

// ---------------------------------------------------------------------------
// Kernel 1 (fused): scores + top-20 in score domain for GA=4 rows of one head.
// UNCHANGED from the verified 392.9us version (r5). Two phases:
//   Phase 1 (8 waves): GEMM, wave owns 4 cols/lane (16 acc), scores -> LDS.
//   Phase 2 (waves 0-3): selection (DPP wave-max, ballot lowest-lane =
//     lowest idx, packed u64 valbits<<32|~idx lists).
//   Phase 3: 4-list merge per row, exact jax.lax.top_k tiebreak.
// ---------------------------------------------------------------------------
__global__ __launch_bounds__(512, 4) void k_scores_topk(
    const float* __restrict__ e1, const float* __restrict__ e2,
    const float* __restrict__ temperature,
    int* __restrict__ topk_idx, float* __restrict__ topk_val)
{
    const int h  = blockIdx.y;
    const int n0 = blockIdx.x * GA;
    const int t  = threadIdx.x;
    const int w  = t >> 6, lane = t & 63;

    __shared__ float e1s[GA][64];
    __shared__ float scoresS[GA][2048];
    __shared__ float red[GA][4];
    __shared__ ull   lists[4][GA][KK + 1];
    __shared__ float selpv[GA][KK];
    __shared__ int   seli[GA][KK];
    __shared__ float ssum[GA];

    if (t < 256)
        e1s[t >> 6][t & 63] = e1[(size_t)(h * NB + n0 + (t >> 6)) * 64 + (t & 63)];
    __syncthreads();

    const float rtemp = 1.f / temperature[h];
    const float* __restrict__ e2h = e2 + (size_t)h * 64 * NB;

    // ---- phase 1: GEMM, 8 waves, 4 cols per lane (16 accumulators) ----
    {
        const int mb1 = w * 256 + lane * 4;           // this lane's 4 cols
        const int ml1 = (mb1 < NB) ? mb1 : (NB - 4);  // clamp tail (dup cols)

        float acc[GA][4];
#pragma unroll
        for (int r = 0; r < GA; r++)
#pragma unroll
            for (int c = 0; c < 4; c++) acc[r][c] = 0.f;

        for (int d4 = 0; d4 < 64; d4 += 4) {
            float4 ev0 = *(const float4*)&e1s[0][d4];
            float4 ev1 = *(const float4*)&e1s[1][d4];
            float4 ev2 = *(const float4*)&e1s[2][d4];
            float4 ev3 = *(const float4*)&e1s[3][d4];
#pragma unroll
            for (int dd = 0; dd < 4; dd++) {
                float4 a = *(const float4*)(e2h + (size_t)(d4 + dd) * NB + ml1);
                float f0 = COMP(ev0, dd), f1 = COMP(ev1, dd);
                float f2 = COMP(ev2, dd), f3 = COMP(ev3, dd);
                acc[0][0] += f0*a.x; acc[0][1] += f0*a.y; acc[0][2] += f0*a.z; acc[0][3] += f0*a.w;
                acc[1][0] += f1*a.x; acc[1][1] += f1*a.y; acc[1][2] += f1*a.z; acc[1][3] += f1*a.w;
                acc[2][0] += f2*a.x; acc[2][1] += f2*a.y; acc[2][2] += f2*a.z; acc[2][3] += f2*a.w;
                acc[3][0] += f3*a.x; acc[3][1] += f3*a.y; acc[3][2] += f3*a.z; acc[3][3] += f3*a.w;
            }
        }

#pragma unroll
        for (int r = 0; r < GA; r++) {
            float4 v; v.x = acc[r][0]; v.y = acc[r][1]; v.z = acc[r][2]; v.w = acc[r][3];
            *(float4*)&scoresS[r][mb1] = v;   // slot by UNCLAMPED col; tail sentineled below
        }
    }
    __syncthreads();

    // ---- phases 2+3: selection, waves 0-3 only ----
    if (w < 4) {
        const int  mbase = w * 512 + lane * 8;
        const bool valid = (mbase < NB);            // all-8-or-none (NB%8==0)

        float acc[GA][8];
#pragma unroll
        for (int r = 0; r < GA; r++) {
            float4 lo = *(const float4*)&scoresS[r][mbase];
            float4 hi = *(const float4*)&scoresS[r][mbase + 4];
            acc[r][0] = lo.x; acc[r][1] = lo.y; acc[r][2] = lo.z; acc[r][3] = lo.w;
            acc[r][4] = hi.x; acc[r][5] = hi.y; acc[r][6] = hi.z; acc[r][7] = hi.w;
        }

        // tv = relu(acc)*rtemp ; invalid tail lanes -> -1 sentinel
#pragma unroll
        for (int r = 0; r < GA; r++) {
            float tvm = -1.f;
#pragma unroll
            for (int k = 0; k < 8; k++) {
                float v = valid ? fmaxf(acc[r][k], 0.f) * rtemp : -1.f;
                acc[r][k] = v;
                tvm = fmaxf(tvm, v);
            }
            tvm = wavemax63(tvm);
            if (lane == 63) red[r][w] = tvm;   // slice max (for exp shift)
        }

        // running per-lane local argmax for each row (strict > keeps lowest k)
        float lm[GA]; int ak[GA];
#pragma unroll
        for (int r = 0; r < GA; r++) {
            float l = acc[r][0]; int a = 0;
#pragma unroll
            for (int k = 1; k < 8; k++)
                if (acc[r][k] > l) { l = acc[r][k]; a = k; }
            lm[r] = l; ak[r] = a;
        }

        // selection: 20 rounds; per round all 4 rows' DPP chains interleaved
        for (int round = 0; round < KK; round++) {
            float M[GA];
#pragma unroll
            for (int r = 0; r < GA; r++) M[r] = lm[r];
#pragma unroll
            for (int r = 0; r < GA; r++) M[r] = dppmax<0x111>(M[r]);
#pragma unroll
            for (int r = 0; r < GA; r++) M[r] = dppmax<0x112>(M[r]);
#pragma unroll
            for (int r = 0; r < GA; r++) M[r] = dppmax<0x114>(M[r]);
#pragma unroll
            for (int r = 0; r < GA; r++) M[r] = dppmax<0x118>(M[r]);
#pragma unroll
            for (int r = 0; r < GA; r++) M[r] = dppmax<0x142>(M[r]);
#pragma unroll
            for (int r = 0; r < GA; r++) M[r] = dppmax<0x143>(M[r]);
#pragma unroll
            for (int r = 0; r < GA; r++)
                M[r] = __builtin_bit_cast(float,
                         __builtin_amdgcn_readlane(__builtin_bit_cast(int, M[r]), 63));
#pragma unroll
            for (int r = 0; r < GA; r++) {
                ull ball = __ballot(lm[r] == M[r]);
                int wl   = __ffsll(ball) - 1;       // lowest lane = lowest global idx
                if (lane == wl) {
                    int gidx = mbase + ak[r];
                    lists[w][r][round] =
                        ((ull)__float_as_uint(M[r]) << 32) | (unsigned)~gidx;
#pragma unroll
                    for (int k = 0; k < 8; k++) if (k == ak[r]) acc[r][k] = -2.f;
                    float l = acc[r][0]; int a = 0;
#pragma unroll
                    for (int k = 1; k < 8; k++)
                        if (acc[r][k] > l) { l = acc[r][k]; a = k; }
                    lm[r] = l; ak[r] = a;
                }
            }
        }
#pragma unroll
        for (int r = 0; r < GA; r++)
            if (lane == 0) lists[w][r][KK] = 0ULL;  // merge sentinel
    }
    __syncthreads();

    // merge 4 sorted lists per row; lanes 0..3 of wave 0 handle one row each
    if (t < GA) {
        const int r = t;
        float mx = fmaxf(fmaxf(red[r][0], red[r][1]), fmaxf(red[r][2], red[r][3]));
        int p0 = 0, p1 = 0, p2 = 0, p3 = 0;
        ull h0 = lists[0][r][0], h1 = lists[1][r][0];
        ull h2 = lists[2][r][0], h3 = lists[3][r][0];
        float ss = 0.f;
        for (int q = 0; q < KK; q++) {
            ull a_ = h0 >= h1 ? h0 : h1; int wa = h0 >= h1 ? 0 : 1;
            ull b_ = h2 >= h3 ? h2 : h3; int wb = h2 >= h3 ? 2 : 3;
            ull bk = a_ >= b_ ? a_ : b_; int bw = a_ >= b_ ? wa : wb;
            float tvv = __uint_as_float((unsigned)(bk >> 32));
            float pv  = __expf(tvv - mx);
            selpv[r][q] = pv;
            seli[r][q]  = (int)~(unsigned)bk;
            ss += pv;
            if      (bw == 0) h0 = lists[0][r][++p0];
            else if (bw == 1) h1 = lists[1][r][++p1];
            else if (bw == 2) h2 = lists[2][r][++p2];
            else              h3 = lists[3][r][++p3];
        }
        ssum[r] = ss;
    }
    __syncthreads();

    if (t < GA * KK) {
        int r = t / KK, q = t % KK;
        int o = (h * NB + n0 + r) * KK + q;
        topk_idx[o] = seli[r][q];
        topk_val[o] = selpv[r][q] / (ssum[r] + EPSF);
    }
}

// ---------------------------------------------------------------------------
// Kernel 2: final_adj row i; writes dense fp32 fadj (output) and scatters
// nonzeros into bf16 A-matrix faT_b[m=i][k=j] (pre-zeroed, K padded to 2048).
// ---------------------------------------------------------------------------
__global__ __launch_bounds__(256) void k_final_adj(
    const int* __restrict__ topk_idx, const float* __restrict__ topk_val,
    const float* __restrict__ ew1, const float* __restrict__ eb1,
    const float* __restrict__ ew2, const float* __restrict__ eb2,
    float* __restrict__ fadj_out, ushort* __restrict__ faT_b)
{
    const int i = blockIdx.x;
    const int t = threadIdx.x;

    __shared__ float rows[HH][NB];
    __shared__ float w1[32];
    __shared__ float b1[8];
    __shared__ float w2[8];
    __shared__ float b2v;

    for (int k = t; k < HH * NB; k += 256) ((float*)rows)[k] = 0.f;
    if (t < 32) w1[t] = ew1[t];
    if (t < 8)  { b1[t] = eb1[t]; w2[t] = ew2[t]; }
    if (t == 0) b2v = eb2[0];
    __syncthreads();

    if (t < HH * KK) {
        int h = t / KK, r = t % KK;
        int o = (h * NB + i) * KK + r;
        rows[h][topk_idx[o]] = topk_val[o];
    }
    __syncthreads();

#pragma unroll
    for (int k = 0; k < 8; k++) {
        int j = k * 256 + t;
        if (j < NB) {
            float f0 = rows[0][j], f1 = rows[1][j], f2 = rows[2][j], f3 = rows[3][j];
            float mean = (f0 + f1 + f2 + f3) * 0.25f;
            float outv = 0.f;
            if (mean > 0.f) {
                float ewv = b2v;
#pragma unroll
                for (int c = 0; c < 8; c++) {
                    float hid = f0 * w1[c] + f1 * w1[8 + c] + f2 * w1[16 + c] + f3 * w1[24 + c] + b1[c];
                    hid = fmaxf(hid, 0.f);
                    ewv += hid * w2[c];
                }
                float sig = 1.f / (1.f + expf(-ewv));
                outv = sig * mean;
                faT_b[(size_t)j * KP + i] = f2bf(outv);  // A[m=i][k=j] scatter
            }
            fadj_out[(size_t)i * NB + j] = outv;
        }
    }
}

// ---------------------------------------------------------------------------
// Kernel 3 (NEW, fused support+transpose): block (jt, bl), bl = b*32+l.
// Computes support[j][c] for 64 j's x 64 c's (c = bl*64+d) and writes the
// 64x64 tile TRANSPOSED directly into ST[c][j], eliminating the S_b
// intermediate (~100 MB of HBM round-trip) and the k_transpose launch.
// Bit-exact vs the old path: same f2bf(acc) bits land in ST.
// j in [2000,2048) zero-filled (k_gemm reads full KP).
// ---------------------------------------------------------------------------
__global__ __launch_bounds__(256) void k_support_t(
    const float* __restrict__ x, const float* __restrict__ w,
    ushort* __restrict__ ST)
{
    const int jt = blockIdx.x;   // 0..31  j-tile
    const int bl = blockIdx.y;   // 0..127 (b*32 + l)
    const int b_ = bl >> 5, l = bl & 31;
    const int t  = threadIdx.x;

    __shared__ float  xs[64][65];   // [j-local][dd], 65-pad (bank spread)
    __shared__ float  ws[64 * 64];  // [dd][d]
    __shared__ ushort ob[64 * 65];  // [j-local][d] bf16, 65-pad (transpose read)

    for (int k = t; k < 4096; k += 256) ws[k] = w[k];

    {
        const float* xb = x + (size_t)b_ * 4096000 + (size_t)l * 64;
#pragma unroll
        for (int p = 0; p < 4; p++) {
            int q  = p * 256 + t;
            int jl = q >> 4, f4 = q & 15;         // j-local, float4 index
            int jg = jt * 64 + jl;
            int jc = jg < NB ? jg : (NB - 1);     // clamp OOB x read (masked later)
            *(float4*)&xs[jl][f4 * 4] =
                *(const float4*)(xb + (size_t)jc * 2048 + f4 * 4);
        }
    }
    __syncthreads();

    const int dq = t & 15;    // d-quad: d = dq*4..+4
    const int g  = t >> 4;    // j-group: j-local = g*4+r
    float acc[4][4];
#pragma unroll
    for (int r = 0; r < 4; r++)
#pragma unroll
        for (int c = 0; c < 4; c++) acc[r][c] = 0.f;

    for (int dd = 0; dd < 64; dd++) {
        float4 w4 = *(const float4*)&ws[dd * 64 + dq * 4];
#pragma unroll
        for (int r = 0; r < 4; r++) {
            float xv = xs[g * 4 + r][dd];
            acc[r][0] += xv * w4.x;
            acc[r][1] += xv * w4.y;
            acc[r][2] += xv * w4.z;
            acc[r][3] += xv * w4.w;
        }
    }

    // bf16-convert into LDS tile; zero rows for j >= NB (ST padding)
#pragma unroll
    for (int r = 0; r < 4; r++) {
        int jl = g * 4 + r;
        bool jvalid = (jt * 64 + jl) < NB;
        ushort* dst = &ob[jl * 65 + dq * 4];
        dst[0] = jvalid ? f2bf(acc[r][0]) : (ushort)0;
        dst[1] = jvalid ? f2bf(acc[r][1]) : (ushort)0;
        dst[2] = jvalid ? f2bf(acc[r][2]) : (ushort)0;
        dst[3] = jvalid ? f2bf(acc[r][3]) : (ushort)0;
    }
    __syncthreads();

    // transposed write: ST[c][j], c = bl*64 + rc, j = jt*64 + s*8..+8
#pragma unroll
    for (int p = 0; p < 2; p++) {
        int q = p * 256 + t;
        int rc = q >> 3, s = q & 7;
        ushortx8 o;
#pragma unroll
        for (int k = 0; k < 8; k++) o[k] = ob[(s * 8 + k) * 65 + rc];
        *(ushortx8*)&ST[(size_t)(bl * 64 + rc) * KP + jt * 64 + s * 8] = o;
    }
}

// ---------------------------------------------------------------------------
// Kernel 4: MFMA bf16 GEMM: out[i][c] = sum_j A[i][j] * B[c][j]
// global_load_lds width=16 staging; XOR swizzle applied on the GLOBAL fetch
// side (LDS image lane-linear), frag ds_read_b128 conflict-free.
// NEW this round: XCD-aware block swizzle (T1; nwg=1024, 1024%8==0 so the
// simple bijective form is valid). Default round-robin spreads the 16 blocks
// sharing one 512KB B-panel across all 8 XCD L2s (B refetched 8x from L3);
// swizzled, each XCD owns 8 B-panels (4MB, L2-resident).
// ---------------------------------------------------------------------------
__global__ __launch_bounds__(256) void k_gemm(
    const ushort* __restrict__ A, const ushort* __restrict__ B,
    const float* __restrict__ bias, float* __restrict__ out)
{
    __shared__ ushort As[128 * 64];
    __shared__ ushort Bs[128 * 64];

    const int t    = threadIdx.x;
    const int lane = t & 63, wave = t >> 6;
    const int wm   = wave & 1, wn = wave >> 1;

    // XCD swizzle: lin -> (xcd, idx); XCD k owns by' in [k*8, k*8+8)
    const int lin = blockIdx.y * 16 + blockIdx.x;   // dispatch-linear (x fastest)
    const int tl  = (lin & 7) * 128 + (lin >> 3);   // bijective (1024 % 8 == 0)
    const int i0  = (tl & 15) * 128;
    const int c0  = (tl >> 4) * 128;

    const int lr = lane >> 3;   // local row within 8-row chunk
    const int dg = lane & 7;    // LDS dest group (fixed by lane-linear DMA)

    floatx4 acc[4][4];
#pragma unroll
    for (int r = 0; r < 4; r++)
#pragma unroll
        for (int c = 0; c < 4; c++) acc[r][c] = (floatx4)(0.f);

    for (int kb = 0; kb < 32; kb++) {
        __syncthreads();
#pragma unroll
        for (int p = 0; p < 4; p++) {
            int rowb = p * 32 + wave * 8;           // chunk base row (mult of 8)
            int row  = rowb + lr;
            int g    = dg ^ lr;                     // row&7 == lr here
            const ushort* ga = &A[(size_t)(i0 + row) * KP + kb * 64 + g * 8];
            const ushort* gb = &B[(size_t)(c0 + row) * KP + kb * 64 + g * 8];
            gload_lds16(ga, &As[rowb * 64]);
            gload_lds16(gb, &Bs[rowb * 64]);
        }
        __syncthreads();   // compiler emits s_waitcnt vmcnt(0) before barrier

#pragma unroll
        for (int kk = 0; kk < 2; kk++) {
            short8 af[4], bf[4];
            const int gidx = kk * 4 + (lane >> 4);   // global k-group 0..7
            const int dsw  = gidx ^ (lane & 7);      // m&7 == lane&7 for frag rows
#pragma unroll
            for (int r = 0; r < 4; r++) {
                int m = wm * 64 + r * 16 + (lane & 15);
                af[r] = *(const short8*)&As[m * 64 + dsw * 8];
            }
#pragma unroll
            for (int c = 0; c < 4; c++) {
                int m = wn * 64 + c * 16 + (lane & 15);
                bf[c] = *(const short8*)&Bs[m * 64 + dsw * 8];
            }
#pragma unroll
            for (int r = 0; r < 4; r++)
#pragma unroll
                for (int c = 0; c < 4; c++)
                    acc[r][c] = __builtin_amdgcn_mfma_f32_16x16x32_bf16(af[r], bf[c], acc[r][c], 0, 0, 0);
        }
    }

    // epilogue: D layout col = lane&15, row = (lane>>4)*4 + reg  [m89-verified]
    const int mq = (lane >> 4) * 4;
    const int nn = lane & 15;
#pragma unroll
    for (int r = 0; r < 4; r++) {
#pragma unroll
        for (int c = 0; c < 4; c++) {
            int cg = c0 + wn * 64 + c * 16 + nn;
            float bv = bias[cg & 63];
            int b_ = cg >> 11, rem = cg & 2047;
            float* op = out + (size_t)b_ * 4096000 + rem;
#pragma unroll
            for (int rg = 0; rg < 4; rg++) {
                int i = i0 + wm * 64 + r * 16 + mq + rg;
                if (i < NB) op[(size_t)i * 2048] = acc[r][c][rg] + bv;
            }
        }
    }
}

// ---------------------------------------------------------------------------
extern "C" void kernel_launch(void* const* d_in, const int* in_sizes, int n_in,
                              void* d_out, int out_size, void* d_ws, size_t ws_size,
                              hipStream_t stream)
{
    const float* x           = (const float*)d_in[0];
    const float* e1          = (const float*)d_in[1];
    const float* e2          = (const float*)d_in[2];
    const float* temperature = (const float*)d_in[3];
    const float* ew1         = (const float*)d_in[4];
    const float* eb1         = (const float*)d_in[5];
    const float* ew2         = (const float*)d_in[6];
    const float* eb2         = (const float*)d_in[7];
    const float* weight      = (const float*)d_in[8];
    const float* bias        = (const float*)d_in[9];

    float* out  = (float*)d_out;            // (B,N,L,DOUT) = 16,384,000 floats
    float* fadj = out + 16384000;           // (N,N)        =  4,000,000 floats

    // workspace (S_b eliminated this round):
    //   ST    bf16 8192xKP = 33,554,432 B
    //   faT_b bf16 KPxKP   =  8,388,608 B
    //   topk  idx+val      =  1,280,000 B      total ~43.2 MB
    ushort* ST       = (ushort*)d_ws;
    ushort* faT_b    = ST + (size_t)8192 * KP;
    int*    topk_idx = (int*)(faT_b + (size_t)KP * KP);
    float*  topk_val = (float*)(topk_idx + 160000);

    hipMemsetAsync(faT_b, 0, (size_t)KP * KP * sizeof(ushort), stream);

    k_scores_topk<<<dim3(NB / GA, HH), 512, 0, stream>>>(e1, e2, temperature,
                                                         topk_idx, topk_val);
    k_final_adj<<<NB, 256, 0, stream>>>(topk_idx, topk_val, ew1, eb1, ew2, eb2,
                                        fadj, faT_b);
    k_support_t<<<dim3(32, 128), 256, 0, stream>>>(x, weight, ST);
    k_gemm<<<dim3(16, 64), 256, 0, stream>>>(faT_b, ST, bias, out);
}

// Round 7
// 361.726 us; speedup vs baseline: 1.1181x; 1.0291x over previous
//
#include <hip/hip_runtime.h>

#define NB   2000   // N
#define HH   4      // heads
#define KK   20     // topk
#define KP   2048   // padded K (j) dim for GEMM
#define GA   4      // rows per k_scores_topk block
#define EPSF 1e-8f

typedef unsigned short ushort;
typedef unsigned long long ull;
using short8   = __attribute__((ext_vector_type(8))) short;
using floatx4  = __attribute__((ext_vector_type(4))) float;
using ushortx4 = __attribute__((ext_vector_type(4))) unsigned short;
using ushortx8 = __attribute__((ext_vector_type(8))) unsigned short;

__device__ inline ushort f2bf(float f) {
    unsigned u = __builtin_bit_cast(unsigned, f);
    u += 0x7fffu + ((u >> 16) & 1u);   // round-to-nearest-even
    return (ushort)(u >> 16);
}

__device__ __forceinline__ void gload_lds16(const ushort* g, ushort* l) {
    __builtin_amdgcn_global_load_lds(
        (const __attribute__((address_space(1))) void*)g,
        (__attribute__((address_space(3))) void*)l, 16, 0, 0);
}

// VALU-only DPP max step: x = max(x, dpp_move(x, CTRL)). Invalid source
// lanes keep old (=x), which is identity for max.
template<int CTRL>
__device__ __forceinline__ float dppmax(float x) {
    int xi = __builtin_bit_cast(int, x);
    int yi = __builtin_amdgcn_update_dpp(xi, xi, CTRL, 0xF, 0xF, false);
    return fmaxf(x, __builtin_bit_cast(float, yi));
}

// After this chain lane 63 holds the wave-wide max (gfx9 wave64 pattern).
__device__ __forceinline__ float wavemax63(float x) {
    x = dppmax<0x111>(x);   // row_shr:1
    x = dppmax<0x112>(x);   // row_shr:2
    x = dppmax<0x114>(x);   // row_shr:4
    x = dppmax<0x118>(x);   // row_shr:8
    x = dppmax<0x142>(x);   // row_bcast:15
    x = dppmax<0x143>(x);   // row_bcast:31
    return x;
}

#define COMP(v,i) ((i)==0?(v).x:(i)==1?(v).y:(i)==2?(v).z:(v).w)

// ---------------------------------------------------------------------------
// Kernel 1 (fused): scores + top-20 in score domain for GA=4 rows of one head.
// UNCHANGED (verified, ~121us). Two phases:
//   Phase 1 (8 waves): GEMM, wave owns 4 cols/lane (16 acc), scores -> LDS.
//   Phase 2 (waves 0-3): selection (DPP wave-max, ballot lowest-lane =
//     lowest idx, packed u64 valbits<<32|~idx lists).
//   Phase 3: 4-list merge per row, exact jax.lax.top_k tiebreak.
// ---------------------------------------------------------------------------
__global__ __launch_bounds__(512, 4) void k_scores_topk(
    const float* __restrict__ e1, const float* __restrict__ e2,
    const float* __restrict__ temperature,
    int* __restrict__ topk_idx, float* __restrict__ topk_val)
{
    const int h  = blockIdx.y;
    const int n0 = blockIdx.x * GA;
    const int t  = threadIdx.x;
    const int w  = t >> 6, lane = t & 63;

    __shared__ float e1s[GA][64];
    __shared__ float scoresS[GA][2048];
    __shared__ float red[GA][4];
    __shared__ ull   lists[4][GA][KK + 1];
    __shared__ float selpv[GA][KK];
    __shared__ int   seli[GA][KK];
    __shared__ float ssum[GA];

    if (t < 256)
        e1s[t >> 6][t & 63] = e1[(size_t)(h * NB + n0 + (t >> 6)) * 64 + (t & 63)];
    __syncthreads();

    const float rtemp = 1.f / temperature[h];
    const float* __restrict__ e2h = e2 + (size_t)h * 64 * NB;

    // ---- phase 1: GEMM, 8 waves, 4 cols per lane (16 accumulators) ----
    {
        const int mb1 = w * 256 + lane * 4;           // this lane's 4 cols
        const int ml1 = (mb1 < NB) ? mb1 : (NB - 4);  // clamp tail (dup cols)

        float acc[GA][4];
#pragma unroll
        for (int r = 0; r < GA; r++)
#pragma unroll
            for (int c = 0; c < 4; c++) acc[r][c] = 0.f;

        for (int d4 = 0; d4 < 64; d4 += 4) {
            float4 ev0 = *(const float4*)&e1s[0][d4];
            float4 ev1 = *(const float4*)&e1s[1][d4];
            float4 ev2 = *(const float4*)&e1s[2][d4];
            float4 ev3 = *(const float4*)&e1s[3][d4];
#pragma unroll
            for (int dd = 0; dd < 4; dd++) {
                float4 a = *(const float4*)(e2h + (size_t)(d4 + dd) * NB + ml1);
                float f0 = COMP(ev0, dd), f1 = COMP(ev1, dd);
                float f2 = COMP(ev2, dd), f3 = COMP(ev3, dd);
                acc[0][0] += f0*a.x; acc[0][1] += f0*a.y; acc[0][2] += f0*a.z; acc[0][3] += f0*a.w;
                acc[1][0] += f1*a.x; acc[1][1] += f1*a.y; acc[1][2] += f1*a.z; acc[1][3] += f1*a.w;
                acc[2][0] += f2*a.x; acc[2][1] += f2*a.y; acc[2][2] += f2*a.z; acc[2][3] += f2*a.w;
                acc[3][0] += f3*a.x; acc[3][1] += f3*a.y; acc[3][2] += f3*a.z; acc[3][3] += f3*a.w;
            }
        }

#pragma unroll
        for (int r = 0; r < GA; r++) {
            float4 v; v.x = acc[r][0]; v.y = acc[r][1]; v.z = acc[r][2]; v.w = acc[r][3];
            *(float4*)&scoresS[r][mb1] = v;   // slot by UNCLAMPED col; tail sentineled below
        }
    }
    __syncthreads();

    // ---- phases 2+3: selection, waves 0-3 only ----
    if (w < 4) {
        const int  mbase = w * 512 + lane * 8;
        const bool valid = (mbase < NB);            // all-8-or-none (NB%8==0)

        float acc[GA][8];
#pragma unroll
        for (int r = 0; r < GA; r++) {
            float4 lo = *(const float4*)&scoresS[r][mbase];
            float4 hi = *(const float4*)&scoresS[r][mbase + 4];
            acc[r][0] = lo.x; acc[r][1] = lo.y; acc[r][2] = lo.z; acc[r][3] = lo.w;
            acc[r][4] = hi.x; acc[r][5] = hi.y; acc[r][6] = hi.z; acc[r][7] = hi.w;
        }

        // tv = relu(acc)*rtemp ; invalid tail lanes -> -1 sentinel
#pragma unroll
        for (int r = 0; r < GA; r++) {
            float tvm = -1.f;
#pragma unroll
            for (int k = 0; k < 8; k++) {
                float v = valid ? fmaxf(acc[r][k], 0.f) * rtemp : -1.f;
                acc[r][k] = v;
                tvm = fmaxf(tvm, v);
            }
            tvm = wavemax63(tvm);
            if (lane == 63) red[r][w] = tvm;   // slice max (for exp shift)
        }

        // running per-lane local argmax for each row (strict > keeps lowest k)
        float lm[GA]; int ak[GA];
#pragma unroll
        for (int r = 0; r < GA; r++) {
            float l = acc[r][0]; int a = 0;
#pragma unroll
            for (int k = 1; k < 8; k++)
                if (acc[r][k] > l) { l = acc[r][k]; a = k; }
            lm[r] = l; ak[r] = a;
        }

        // selection: 20 rounds; per round all 4 rows' DPP chains interleaved
        for (int round = 0; round < KK; round++) {
            float M[GA];
#pragma unroll
            for (int r = 0; r < GA; r++) M[r] = lm[r];
#pragma unroll
            for (int r = 0; r < GA; r++) M[r] = dppmax<0x111>(M[r]);
#pragma unroll
            for (int r = 0; r < GA; r++) M[r] = dppmax<0x112>(M[r]);
#pragma unroll
            for (int r = 0; r < GA; r++) M[r] = dppmax<0x114>(M[r]);
#pragma unroll
            for (int r = 0; r < GA; r++) M[r] = dppmax<0x118>(M[r]);
#pragma unroll
            for (int r = 0; r < GA; r++) M[r] = dppmax<0x142>(M[r]);
#pragma unroll
            for (int r = 0; r < GA; r++) M[r] = dppmax<0x143>(M[r]);
#pragma unroll
            for (int r = 0; r < GA; r++)
                M[r] = __builtin_bit_cast(float,
                         __builtin_amdgcn_readlane(__builtin_bit_cast(int, M[r]), 63));
#pragma unroll
            for (int r = 0; r < GA; r++) {
                ull ball = __ballot(lm[r] == M[r]);
                int wl   = __ffsll(ball) - 1;       // lowest lane = lowest global idx
                if (lane == wl) {
                    int gidx = mbase + ak[r];
                    lists[w][r][round] =
                        ((ull)__float_as_uint(M[r]) << 32) | (unsigned)~gidx;
#pragma unroll
                    for (int k = 0; k < 8; k++) if (k == ak[r]) acc[r][k] = -2.f;
                    float l = acc[r][0]; int a = 0;
#pragma unroll
                    for (int k = 1; k < 8; k++)
                        if (acc[r][k] > l) { l = acc[r][k]; a = k; }
                    lm[r] = l; ak[r] = a;
                }
            }
        }
#pragma unroll
        for (int r = 0; r < GA; r++)
            if (lane == 0) lists[w][r][KK] = 0ULL;  // merge sentinel
    }
    __syncthreads();

    // merge 4 sorted lists per row; lanes 0..3 of wave 0 handle one row each
    if (t < GA) {
        const int r = t;
        float mx = fmaxf(fmaxf(red[r][0], red[r][1]), fmaxf(red[r][2], red[r][3]));
        int p0 = 0, p1 = 0, p2 = 0, p3 = 0;
        ull h0 = lists[0][r][0], h1 = lists[1][r][0];
        ull h2 = lists[2][r][0], h3 = lists[3][r][0];
        float ss = 0.f;
        for (int q = 0; q < KK; q++) {
            ull a_ = h0 >= h1 ? h0 : h1; int wa = h0 >= h1 ? 0 : 1;
            ull b_ = h2 >= h3 ? h2 : h3; int wb = h2 >= h3 ? 2 : 3;
            ull bk = a_ >= b_ ? a_ : b_; int bw = a_ >= b_ ? wa : wb;
            float tvv = __uint_as_float((unsigned)(bk >> 32));
            float pv  = __expf(tvv - mx);
            selpv[r][q] = pv;
            seli[r][q]  = (int)~(unsigned)bk;
            ss += pv;
            if      (bw == 0) h0 = lists[0][r][++p0];
            else if (bw == 1) h1 = lists[1][r][++p1];
            else if (bw == 2) h2 = lists[2][r][++p2];
            else              h3 = lists[3][r][++p3];
        }
        ssum[r] = ss;
    }
    __syncthreads();

    if (t < GA * KK) {
        int r = t / KK, q = t % KK;
        int o = (h * NB + n0 + r) * KK + q;
        topk_idx[o] = seli[r][q];
        topk_val[o] = selpv[r][q] / (ssum[r] + EPSF);
    }
}

// ---------------------------------------------------------------------------
// Kernel 2: final_adj row i; writes dense fp32 fadj (output) and scatters
// nonzeros into bf16 A-matrix faT_b[m=i][k=j] (pre-zeroed, K padded to 2048).
// ---------------------------------------------------------------------------
__global__ __launch_bounds__(256) void k_final_adj(
    const int* __restrict__ topk_idx, const float* __restrict__ topk_val,
    const float* __restrict__ ew1, const float* __restrict__ eb1,
    const float* __restrict__ ew2, const float* __restrict__ eb2,
    float* __restrict__ fadj_out, ushort* __restrict__ faT_b)
{
    const int i = blockIdx.x;
    const int t = threadIdx.x;

    __shared__ float rows[HH][NB];
    __shared__ float w1[32];
    __shared__ float b1[8];
    __shared__ float w2[8];
    __shared__ float b2v;

    for (int k = t; k < HH * NB; k += 256) ((float*)rows)[k] = 0.f;
    if (t < 32) w1[t] = ew1[t];
    if (t < 8)  { b1[t] = eb1[t]; w2[t] = ew2[t]; }
    if (t == 0) b2v = eb2[0];
    __syncthreads();

    if (t < HH * KK) {
        int h = t / KK, r = t % KK;
        int o = (h * NB + i) * KK + r;
        rows[h][topk_idx[o]] = topk_val[o];
    }
    __syncthreads();

#pragma unroll
    for (int k = 0; k < 8; k++) {
        int j = k * 256 + t;
        if (j < NB) {
            float f0 = rows[0][j], f1 = rows[1][j], f2 = rows[2][j], f3 = rows[3][j];
            float mean = (f0 + f1 + f2 + f3) * 0.25f;
            float outv = 0.f;
            if (mean > 0.f) {
                float ewv = b2v;
#pragma unroll
                for (int c = 0; c < 8; c++) {
                    float hid = f0 * w1[c] + f1 * w1[8 + c] + f2 * w1[16 + c] + f3 * w1[24 + c] + b1[c];
                    hid = fmaxf(hid, 0.f);
                    ewv += hid * w2[c];
                }
                float sig = 1.f / (1.f + expf(-ewv));
                outv = sig * mean;
                faT_b[(size_t)j * KP + i] = f2bf(outv);  // A[m=i][k=j] scatter
            }
            fadj_out[(size_t)i * NB + j] = outv;
        }
    }
}

// ---------------------------------------------------------------------------
// Kernel 3 (fused support+transpose): block (jt, bl), bl = b*32+l.
// Computes support[j][c] for 64 j's x 64 c's and writes the 64x64 tile
// TRANSPOSED directly into ST[c][j]. j in [2000,2048) zero-filled.
// ---------------------------------------------------------------------------
__global__ __launch_bounds__(256) void k_support_t(
    const float* __restrict__ x, const float* __restrict__ w,
    ushort* __restrict__ ST)
{
    const int jt = blockIdx.x;   // 0..31  j-tile
    const int bl = blockIdx.y;   // 0..127 (b*32 + l)
    const int b_ = bl >> 5, l = bl & 31;
    const int t  = threadIdx.x;

    __shared__ float  xs[64][65];   // [j-local][dd], 65-pad (bank spread)
    __shared__ float  ws[64 * 64];  // [dd][d]
    __shared__ ushort ob[64 * 65];  // [j-local][d] bf16, 65-pad (transpose read)

    for (int k = t; k < 4096; k += 256) ws[k] = w[k];

    {
        const float* xb = x + (size_t)b_ * 4096000 + (size_t)l * 64;
#pragma unroll
        for (int p = 0; p < 4; p++) {
            int q  = p * 256 + t;
            int jl = q >> 4, f4 = q & 15;         // j-local, float4 index
            int jg = jt * 64 + jl;
            int jc = jg < NB ? jg : (NB - 1);     // clamp OOB x read (masked later)
            *(float4*)&xs[jl][f4 * 4] =
                *(const float4*)(xb + (size_t)jc * 2048 + f4 * 4);
        }
    }
    __syncthreads();

    const int dq = t & 15;    // d-quad: d = dq*4..+4
    const int g  = t >> 4;    // j-group: j-local = g*4+r
    float acc[4][4];
#pragma unroll
    for (int r = 0; r < 4; r++)
#pragma unroll
        for (int c = 0; c < 4; c++) acc[r][c] = 0.f;

    for (int dd = 0; dd < 64; dd++) {
        float4 w4 = *(const float4*)&ws[dd * 64 + dq * 4];
#pragma unroll
        for (int r = 0; r < 4; r++) {
            float xv = xs[g * 4 + r][dd];
            acc[r][0] += xv * w4.x;
            acc[r][1] += xv * w4.y;
            acc[r][2] += xv * w4.z;
            acc[r][3] += xv * w4.w;
        }
    }

    // bf16-convert into LDS tile; zero rows for j >= NB (ST padding)
#pragma unroll
    for (int r = 0; r < 4; r++) {
        int jl = g * 4 + r;
        bool jvalid = (jt * 64 + jl) < NB;
        ushort* dst = &ob[jl * 65 + dq * 4];
        dst[0] = jvalid ? f2bf(acc[r][0]) : (ushort)0;
        dst[1] = jvalid ? f2bf(acc[r][1]) : (ushort)0;
        dst[2] = jvalid ? f2bf(acc[r][2]) : (ushort)0;
        dst[3] = jvalid ? f2bf(acc[r][3]) : (ushort)0;
    }
    __syncthreads();

    // transposed write: ST[c][j], c = bl*64 + rc, j = jt*64 + s*8..+8
#pragma unroll
    for (int p = 0; p < 2; p++) {
        int q = p * 256 + t;
        int rc = q >> 3, s = q & 7;
        ushortx8 o;
#pragma unroll
        for (int k = 0; k < 8; k++) o[k] = ob[(s * 8 + k) * 65 + rc];
        *(ushortx8*)&ST[(size_t)(bl * 64 + rc) * KP + jt * 64 + s * 8] = o;
    }
}

// ---------------------------------------------------------------------------
// Kernel 4: MFMA bf16 GEMM: out[i][c] = sum_j A[i][j] * B[c][j]
// REWRITTEN (this round): 256x256 tile, 8 waves, double-buffered LDS with
// counted vmcnt. Rationale: the 128^2 m97-structure is LDS-read- and
// panel-traffic-bound at this shape (16 ds_read_b128 (~192cy) per 32 MFMA
// (~155cy) per K-tile per wave; 1024 blocks x 1MB panel traffic ~1GB through
// L3 with 12MB/XCD working set >> 4MB L2). 256^2: ds:MFMA = 24:64 (2.3x less
// LDS-read per FLOP), panel traffic halved, and stage(k+1) overlaps
// compute(k) via s_waitcnt vmcnt(8) + raw s_barrier (loads cross barriers,
// no vmcnt(0) drain). Race-freedom: stage target buffer's readers finished
// before previous trailing barrier; vmcnt retires in issue order; barrier
// after own-vmcnt gives cross-wave visibility. Last iter drains vmcnt(0)
// (no dangling LDS writes at endpgm). Grid 256 blocks = 1/CU; XCD swizzle.
// Same verified XOR swizzle scheme: global-side g=dg^lr, read-side
// dsw=gidx^(m&7).
// ---------------------------------------------------------------------------
__global__ __launch_bounds__(512, 2) void k_gemm(
    const ushort* __restrict__ A, const ushort* __restrict__ B,
    const float* __restrict__ bias, float* __restrict__ out)
{
    __shared__ ushort As[2][256 * 64];   // 64 KB
    __shared__ ushort Bs[2][256 * 64];   // 64 KB

    const int t    = threadIdx.x;
    const int lane = t & 63, wave = t >> 6;   // 8 waves
    const int wm   = wave & 1;                // M half   (128 rows)
    const int wn   = wave >> 1;               // N quarter (64 cols)

    // XCD swizzle (nwg=256, 256%8==0, cpx=32): XCD k gets 8 i-panels x 4 c-panels
    const int lin = blockIdx.y * 8 + blockIdx.x;
    const int swz = (lin & 7) * 32 + (lin >> 3);
    const int i0  = (swz & 7) * 256;
    const int c0  = (swz >> 3) * 256;

    const int lr = lane >> 3;   // local row within 8-row chunk
    const int dg = lane & 7;    // LDS dest group (lane-linear DMA)

    floatx4 acc[8][4];
#pragma unroll
    for (int r = 0; r < 8; r++)
#pragma unroll
        for (int c = 0; c < 4; c++) acc[r][c] = (floatx4)(0.f);

    // stage K-tile kb into buffer buf: wave stages A rows [wave*32,+32) and B likewise
#define STAGE(buf, kb)                                                         \
    {                                                                          \
        _Pragma("unroll")                                                      \
        for (int p = 0; p < 4; p++) {                                          \
            int rowb = wave * 32 + p * 8;                                      \
            int row  = rowb + lr;                                              \
            int g    = dg ^ lr;                                                \
            gload_lds16(&A[(size_t)(i0 + row) * KP + (kb) * 64 + g * 8],       \
                        &As[buf][rowb * 64]);                                  \
            gload_lds16(&B[(size_t)(c0 + row) * KP + (kb) * 64 + g * 8],       \
                        &Bs[buf][rowb * 64]);                                  \
        }                                                                      \
    }

    STAGE(0, 0);
    int cur = 0;

    for (int kb = 0; kb < 32; kb++) {
        if (kb < 31) {
            STAGE(cur ^ 1, kb + 1);                      // 8 newer loads in flight
            asm volatile("s_waitcnt vmcnt(8)" ::: "memory");  // own cur-tile loads done
        } else {
            asm volatile("s_waitcnt vmcnt(0)" ::: "memory");  // drain (also for endpgm)
        }
        __builtin_amdgcn_s_barrier();                    // all waves' cur loads landed
        __builtin_amdgcn_sched_barrier(0);               // no ds_read hoist above barrier

#pragma unroll
        for (int kk = 0; kk < 2; kk++) {
            short8 af[8], bf[4];
            const int gidx = kk * 4 + (lane >> 4);       // global k-group 0..7
            const int dsw  = gidx ^ (lane & 7);          // m&7 == lane&7 for frag rows
#pragma unroll
            for (int r = 0; r < 8; r++) {
                int m = wm * 128 + r * 16 + (lane & 15);
                af[r] = *(const short8*)&As[cur][m * 64 + dsw * 8];
            }
#pragma unroll
            for (int c = 0; c < 4; c++) {
                int m = wn * 64 + c * 16 + (lane & 15);
                bf[c] = *(const short8*)&Bs[cur][m * 64 + dsw * 8];
            }
#pragma unroll
            for (int r = 0; r < 8; r++)
#pragma unroll
                for (int c = 0; c < 4; c++)
                    acc[r][c] = __builtin_amdgcn_mfma_f32_16x16x32_bf16(af[r], bf[c], acc[r][c], 0, 0, 0);
        }

        __builtin_amdgcn_s_barrier();                    // readers done before next STAGE
        cur ^= 1;
    }
#undef STAGE

    // epilogue: D layout col = lane&15, row = (lane>>4)*4 + reg  [m89-verified]
    const int mq = (lane >> 4) * 4;
    const int nn = lane & 15;
#pragma unroll
    for (int r = 0; r < 8; r++) {
#pragma unroll
        for (int c = 0; c < 4; c++) {
            int cg = c0 + wn * 64 + c * 16 + nn;
            float bv = bias[cg & 63];
            int b_ = cg >> 11, rem = cg & 2047;
            float* op = out + (size_t)b_ * 4096000 + rem;
#pragma unroll
            for (int rg = 0; rg < 4; rg++) {
                int i = i0 + wm * 128 + r * 16 + mq + rg;
                if (i < NB) op[(size_t)i * 2048] = acc[r][c][rg] + bv;
            }
        }
    }
}

// ---------------------------------------------------------------------------
extern "C" void kernel_launch(void* const* d_in, const int* in_sizes, int n_in,
                              void* d_out, int out_size, void* d_ws, size_t ws_size,
                              hipStream_t stream)
{
    const float* x           = (const float*)d_in[0];
    const float* e1          = (const float*)d_in[1];
    const float* e2          = (const float*)d_in[2];
    const float* temperature = (const float*)d_in[3];
    const float* ew1         = (const float*)d_in[4];
    const float* eb1         = (const float*)d_in[5];
    const float* ew2         = (const float*)d_in[6];
    const float* eb2         = (const float*)d_in[7];
    const float* weight      = (const float*)d_in[8];
    const float* bias        = (const float*)d_in[9];

    float* out  = (float*)d_out;            // (B,N,L,DOUT) = 16,384,000 floats
    float* fadj = out + 16384000;           // (N,N)        =  4,000,000 floats

    // workspace:
    //   ST    bf16 8192xKP = 33,554,432 B
    //   faT_b bf16 KPxKP   =  8,388,608 B
    //   topk  idx+val      =  1,280,000 B      total ~43.2 MB
    ushort* ST       = (ushort*)d_ws;
    ushort* faT_b    = ST + (size_t)8192 * KP;
    int*    topk_idx = (int*)(faT_b + (size_t)KP * KP);
    float*  topk_val = (float*)(topk_idx + 160000);

    hipMemsetAsync(faT_b, 0, (size_t)KP * KP * sizeof(ushort), stream);

    k_scores_topk<<<dim3(NB / GA, HH), 512, 0, stream>>>(e1, e2, temperature,
                                                         topk_idx, topk_val);
    k_final_adj<<<NB, 256, 0, stream>>>(topk_idx, topk_val, ew1, eb1, ew2, eb2,
                                        fadj, faT_b);
    k_support_t<<<dim3(32, 128), 256, 0, stream>>>(x, weight, ST);
    k_gemm<<<dim3(8, 32), 512, 0, stream>>>(faT_b, ST, bias, out);
}